// Round 1
// baseline (87.758 us; speedup 1.0000x reference)
//
#include <hip/hip_runtime.h>

// PureAEVComputer radial AEV on MI355X.
// B=16 batches, N=512 atoms, S=4 species, R=16 radial shifts, pad to 1008.
// One wave (64 lanes) per atom i: lanes iterate neighbors j in chunks of 64.
// Each lane keeps acc[64] (s-major: s*16+r). End: 6-step shuffle reduce-scatter
// so lane l owns feature l; lane writes out[row + l]; pad zeroed with float4.

constexpr int B = 16;
constexpr int N = 512;
constexpr int TARGET = 1008;

__global__ __launch_bounds__(256) void aev_radial_kernel(
    const int* __restrict__ species,      // (B, N)
    const float* __restrict__ coordinates,// (B, N, 3)
    float* __restrict__ out)              // (B, N, 1008)
{
    __shared__ float sc[N * 3];
    __shared__ int   ss[N];

    const int tid  = threadIdx.x;
    const int bb   = blockIdx.x >> 7;    // batch index (128 blocks per batch)
    const int tile = blockIdx.x & 127;   // 4-atom tile within batch

    // Stage this batch's coordinates + species into LDS (coalesced).
    const float* cb = coordinates + (size_t)bb * (N * 3);
    for (int idx = tid; idx < N * 3; idx += 256) sc[idx] = cb[idx];
    const int* sb = species + bb * N;
    for (int idx = tid; idx < N; idx += 256) ss[idx] = sb[idx];
    __syncthreads();

    const int wave = tid >> 6;
    const int lane = tid & 63;
    const int i    = tile * 4 + wave;    // this wave's atom

    const float xi = sc[i * 3 + 0];
    const float yi = sc[i * 3 + 1];
    const float zi = sc[i * 3 + 2];

    const float shf[16] = {0.9f, 1.16875f, 1.4375f, 1.70625f, 1.975f, 2.24375f,
                           2.5125f, 2.78125f, 3.05f, 3.31875f, 3.5875f, 3.85625f,
                           4.125f, 4.39375f, 4.6625f, 4.93125f};

    float acc[64];
    #pragma unroll
    for (int k = 0; k < 64; ++k) acc[k] = 0.0f;

    // Neighbor loop: 8 chunks of 64 (lane = j within chunk).
    for (int jc = 0; jc < N; jc += 64) {
        const int j = jc + lane;
        const float xj = sc[j * 3 + 0];   // dword stride 3: coprime w/ 32 banks
        const float yj = sc[j * 3 + 1];
        const float zj = sc[j * 3 + 2];
        const int spj = ss[j];

        const float dx = xi - xj, dy = yi - yj, dz = zi - zj;
        const float sq = dx * dx + dy * dy + dz * dz;
        const float d  = __builtin_amdgcn_sqrtf(sq);

        const bool valid = (d > 0.0f) && (d <= 5.2f);
        // fc = 0.5*cos(pi*d/5.2)+0.5 ; v_cos takes revolutions: d/(2*5.2)
        float fc = 0.5f * __builtin_amdgcn_cosf(d * (1.0f / 10.4f)) + 0.5f;
        fc = valid ? fc : 0.0f;

        const float fc0 = (spj == 0) ? fc : 0.0f;
        const float fc1 = (spj == 1) ? fc : 0.0f;
        const float fc2 = (spj == 2) ? fc : 0.0f;
        const float fc3 = (spj == 3) ? fc : 0.0f;

        #pragma unroll
        for (int r = 0; r < 16; ++r) {
            const float x = d - shf[r];
            // exp(-16*x^2) = 2^(-16*log2(e)*x^2)
            const float core = __builtin_amdgcn_exp2f(-23.083120654223414f * (x * x));
            acc[0 * 16 + r] += core * fc0;
            acc[1 * 16 + r] += core * fc1;
            acc[2 * 16 + r] += core * fc2;
            acc[3 * 16 + r] += core * fc3;
        }
    }

    // Reduce-scatter over 64 lanes: 63 shuffles total; lane l ends with
    // feature l fully summed in acc[0].
    int cnt = 64;
    #pragma unroll
    for (int m = 32; m >= 1; m >>= 1) {
        const int half = cnt >> 1;
        const bool up = (lane & m) != 0;
        #pragma unroll
        for (int k = 0; k < half; ++k) {
            const float keep = up ? acc[k + half] : acc[k];
            const float send = up ? acc[k] : acc[k + half];
            acc[k] = keep + __shfl_xor(send, m, 64);
        }
        cnt = half;
    }

    // Write: 64 real features + zero pad (floats 64..1007 = float4 idx 16..251).
    float* row = out + (size_t)(bb * N + i) * TARGET;
    row[lane] = acc[0];
    float4* row4 = reinterpret_cast<float4*>(row);
    const float4 z4 = make_float4(0.0f, 0.0f, 0.0f, 0.0f);
    #pragma unroll
    for (int idx = 16 + lane; idx < 252; idx += 64) row4[idx] = z4;
}

extern "C" void kernel_launch(void* const* d_in, const int* in_sizes, int n_in,
                              void* d_out, int out_size, void* d_ws, size_t ws_size,
                              hipStream_t stream) {
    const int*   species     = (const int*)d_in[0];
    const float* coordinates = (const float*)d_in[1];
    float*       out         = (float*)d_out;

    // 16 batches * 128 tiles = 2048 blocks; 256 threads = 4 waves = 4 atoms/block.
    dim3 grid(B * 128), block(256);
    hipLaunchKernelGGL(aev_radial_kernel, grid, block, 0, stream,
                       species, coordinates, out);
}

// Round 2
// 80.725 us; speedup vs baseline: 1.0871x; 1.0871x over previous
//
#include <hip/hip_runtime.h>

// PureAEVComputer radial AEV on MI355X — R2: packed-fp32 inner loop.
// B=16, N=512, S=4 species, R=16 shifts, pad to 1008.
// One wave per atom i; lanes = neighbor j within 64-chunk.
// core_r = exp(-16(d-s_r)^2) = exp2(A_r*d - B_r - C*d^2), A/B compile-time.
// Per-lane acc = f2[32] (s-major), packed v_pk_fma accumulate.
// Epilogue: 5-level f2 reduce-scatter + 1 float exchange -> lane l owns feat l.

typedef float f2 __attribute__((ext_vector_type(2)));

constexpr int B = 16;
constexpr int N = 512;
constexpr int TARGET = 1008;

__device__ constexpr float SHF(int r) { return 0.9f + 0.26875f * r; }
constexpr float L16 = 23.083120654223414f;  // 16 * log2(e)

__global__ __launch_bounds__(256) void aev_radial_kernel(
    const int* __restrict__ species,       // (B, N)
    const float* __restrict__ coordinates, // (B, N, 3)
    float* __restrict__ out)               // (B, N, 1008)
{
    __shared__ float4 sc[N];  // xyz + species bits in .w

    const int tid  = threadIdx.x;
    const int bb   = blockIdx.x >> 7;    // batch (128 blocks per batch)
    const int tile = blockIdx.x & 127;   // 4-atom tile

    const float* cb = coordinates + (size_t)bb * (N * 3);
    const int*   sb = species + bb * N;
    for (int a = tid; a < N; a += 256) {
        sc[a] = make_float4(cb[3 * a], cb[3 * a + 1], cb[3 * a + 2],
                            __int_as_float(sb[a]));
    }
    __syncthreads();

    const int wave = tid >> 6;
    const int lane = tid & 63;
    const int i    = tile * 4 + wave;

    const float4 ci = sc[i];

    f2 acc[32];
    #pragma unroll
    for (int k = 0; k < 32; ++k) acc[k] = f2{0.0f, 0.0f};

    for (int jc = 0; jc < N; jc += 64) {
        const float4 cj = sc[jc + lane];           // ds_read_b128, conflict-free
        const float dx = ci.x - cj.x;
        const float dy = ci.y - cj.y;
        const float dz = ci.z - cj.z;
        const float sq = dx * dx + dy * dy + dz * dz;   // = d^2 exactly
        const float d  = __builtin_amdgcn_sqrtf(sq);
        const int spj  = __float_as_int(cj.w);

        const bool valid = (d > 0.0f) && (d <= 5.2f);
        // fc = 0.5*cos(pi*d/5.2)+0.5 ; v_cos takes revolutions: d/10.4
        float fc = 0.5f * __builtin_amdgcn_cosf(d * (1.0f / 10.4f)) + 0.5f;
        fc = valid ? fc : 0.0f;

        const f2 fc0 = {(spj == 0) ? fc : 0.0f, (spj == 0) ? fc : 0.0f};
        const f2 fc1 = {(spj == 1) ? fc : 0.0f, (spj == 1) ? fc : 0.0f};
        const f2 fc2 = {(spj == 2) ? fc : 0.0f, (spj == 2) ? fc : 0.0f};
        const f2 fc3 = {(spj == 3) ? fc : 0.0f, (spj == 3) ? fc : 0.0f};

        const float cd2 = L16 * sq;        // C*d^2, once per pair
        const f2 dd  = {d, d};
        const f2 cdv = {cd2, cd2};

        #pragma unroll
        for (int h = 0; h < 8; ++h) {
            const float s0 = SHF(2 * h), s1 = SHF(2 * h + 1);
            const f2 Av = {2.0f * L16 * s0, 2.0f * L16 * s1};   // literals
            const f2 Bv = {L16 * s0 * s0, L16 * s1 * s1};       // literals
            const f2 e  = dd * Av - (Bv + cdv);   // pk_fma + pk_add
            f2 core;
            core.x = __builtin_amdgcn_exp2f(e.x);
            core.y = __builtin_amdgcn_exp2f(e.y);
            acc[0 * 8 + h] += core * fc0;   // v_pk_fma_f32 x4
            acc[1 * 8 + h] += core * fc1;
            acc[2 * 8 + h] += core * fc2;
            acc[3 * 8 + h] += core * fc3;
        }
    }

    // Reduce-scatter: 5 f2 levels (m=32..2), then one float exchange (m=1).
    int cnt = 32;
    #pragma unroll
    for (int m = 32; m >= 2; m >>= 1) {
        const int half = cnt >> 1;
        const bool up = (lane & m) != 0;
        #pragma unroll
        for (int k = 0; k < half; ++k) {
            const f2 keep = up ? acc[k + half] : acc[k];
            const f2 send = up ? acc[k] : acc[k + half];
            f2 r;
            r.x = __shfl_xor(send.x, m, 64);
            r.y = __shfl_xor(send.y, m, 64);
            acc[k] = keep + r;
        }
        cnt = half;
    }
    // acc[0] = features {2t, 2t+1}, t = lane>>1, split by lane parity subsets.
    const bool hi = (lane & 1) != 0;
    const float send = hi ? acc[0].x : acc[0].y;
    const float recv = __shfl_xor(send, 1, 64);
    const float mine = (hi ? acc[0].y : acc[0].x) + recv;

    float* row = out + (size_t)(bb * N + i) * TARGET;
    row[lane] = mine;
    float4* row4 = reinterpret_cast<float4*>(row);
    const float4 z4 = make_float4(0.0f, 0.0f, 0.0f, 0.0f);
    #pragma unroll
    for (int idx = 16 + lane; idx < 252; idx += 64) row4[idx] = z4;
}

extern "C" void kernel_launch(void* const* d_in, const int* in_sizes, int n_in,
                              void* d_out, int out_size, void* d_ws, size_t ws_size,
                              hipStream_t stream) {
    const int*   species     = (const int*)d_in[0];
    const float* coordinates = (const float*)d_in[1];
    float*       out         = (float*)d_out;

    dim3 grid(B * 128), block(256);  // 4 waves = 4 atoms per block
    hipLaunchKernelGGL(aev_radial_kernel, grid, block, 0, stream,
                       species, coordinates, out);
}